// Round 8
// baseline (528.413 us; speedup 1.0000x reference)
//
#include <hip/hip_runtime.h>
#include <hip/hip_bf16.h>

#define BDIM 2048
#define WDIM 128
#define FDIM 8
#define HDIM 256

typedef __bf16 b8 __attribute__((ext_vector_type(8)));
typedef __bf16 b4 __attribute__((ext_vector_type(4)));
typedef float f32x4 __attribute__((ext_vector_type(4)));

#define L2E  1.44269504088896f
#define L2E2 2.88539008177793f

// workspace layout (bytes), all 16B aligned
#define OFF_RZ  0                 // 256 frags * 1KB (r,z Whh A-frags, pre-scaled by log2e)
#define OFF_N   262144            // 128 frags * 1KB (n Whh A-frags, pre-scaled by 2*log2e)
#define OFF_WIH 393216            // 48 frags * 1KB  (Wih A-frags + bias in k=8, pre-scaled)
#define OFF_WP  442368            // 256 frags * 1KB (Wp B-frags, unscaled)
#define OFF_XB  704512            // 2048*128*8 bf16 = 4194304
// total 4,898,816 B

#define MFMA(a,b,c) __builtin_amdgcn_mfma_f32_16x16x32_bf16((a),(b),(c),0,0,0)

static __device__ __forceinline__ float sig_(float v) {      // tail only (unscaled)
    return __builtin_amdgcn_rcpf(1.0f + __expf(-v));
}
static __device__ __forceinline__ float tanh_(float v) {     // tail only (unscaled)
    return fmaf(-2.0f, __builtin_amdgcn_rcpf(1.0f + __expf(2.0f * v)), 1.0f);
}

// ---------------- pack: weights/x -> bf16 MFMA fragments (log2e pre-scaled) ----------------
// A-frag (16x16x32): lane l holds A[i = l&15][k = kt*32 + (l>>4)*8 + e]
// B-frag:            lane l holds B[k = kt*32 + (l>>4)*8 + e][j = l&15]
__global__ void pack_kernel(const float* __restrict__ x,
                            const float* __restrict__ Wih_f,
                            const float* __restrict__ Whh_f,
                            const float* __restrict__ bih_f,
                            const float* __restrict__ bhh_f,
                            const float* __restrict__ Wp,
                            unsigned char* __restrict__ ws)
{
    int idx = blockIdx.x * 256 + threadIdx.x;
    if (idx < 16384) {                       // r,z Whh A-frags: f = (p*4+2g+nt)*8+kt
        int l = idx & 63, f = idx >> 6;
        int kt = f & 7, nt = (f >> 3) & 1, g = (f >> 4) & 1, p = f >> 5;
        int gch = g * HDIM + 32 * p + 16 * nt + (l & 15);
        int kb = kt * 32 + (l >> 4) * 8;
        b8 v;
        #pragma unroll
        for (int e = 0; e < 8; ++e) v[e] = (__bf16)(L2E * Whh_f[gch * HDIM + kb + e]);
        ((b8*)(ws + OFF_RZ))[idx] = v;
    } else if (idx < 24576) {                // n Whh A-frags: f = mtile*8+kt  (x 2*log2e)
        int j = idx - 16384;
        int l = j & 63, f = j >> 6;
        int kt = f & 7, m = f >> 3;
        int gch = 2 * HDIM + 16 * m + (l & 15);
        int kb = kt * 32 + (l >> 4) * 8;
        b8 v;
        #pragma unroll
        for (int e = 0; e < 8; ++e) v[e] = (__bf16)(L2E2 * Whh_f[gch * HDIM + kb + e]);
        ((b8*)(ws + OFF_N))[j] = v;
    } else if (idx < 27648) {                // Wih A-frags: f = (p*3+g)*2+nt (bias at k=8)
        int j = idx - 24576;
        int l = j & 63, f = j >> 6;
        int nt = f & 1, q = f >> 1, g = q % 3, p = q / 3;
        int gch = g * HDIM + 32 * p + 16 * nt + (l & 15);
        int lq = l >> 4;
        float sc = (g == 2) ? L2E2 : L2E;
        b8 v;
        #pragma unroll
        for (int e = 0; e < 8; ++e) v[e] = (__bf16)0.0f;
        if (lq == 0) {
            #pragma unroll
            for (int e = 0; e < 8; ++e) v[e] = (__bf16)(sc * Wih_f[gch * FDIM + e]);
        } else if (lq == 1) {
            float b = (g == 2) ? (L2E2 * bih_f[gch]) : (L2E * (bih_f[gch] + bhh_f[gch]));
            v[0] = (__bf16)b;                // pairs with 1.0 in x B-frag k=8
        }
        ((b8*)(ws + OFF_WIH))[j] = v;
    } else if (idx < 44032) {                // Wp B-frags (unscaled)
        int j = idx - 27648;
        int l = j & 63, nk = j >> 6;
        int NT = nk >> 4, kt = nk & 15;
        int col = NT * 16 + (l & 15);
        int kb = kt * 32 + (l >> 4) * 8;
        b8 v;
        #pragma unroll
        for (int e = 0; e < 8; ++e) v[e] = (__bf16)Wp[col * (2 * HDIM) + kb + e];
        ((b8*)(ws + OFF_WP))[j] = v;
    } else if (idx < 44032 + 262144) {       // x -> bf16 rows [row][t][8]
        int j = idx - 44032;
        const float* src = x + j * 8;
        b8 v;
        #pragma unroll
        for (int e = 0; e < 8; ++e) v[e] = (__bf16)src[e];
        ((b8*)(ws + OFF_XB))[j] = v;
    }
}

// ---------------- fused GRU: 128 blocks x 512 threads (8 waves), 16 rows/block ----------------
// Wave w owns gate channels [32w, 32w+32) of r, z, n (2 M-tiles each).
// ALL weights (48 Whh + 6 Wih frags = 216 regs) pinned in AGPRs ("a" class);
// arch VGPRs hold only the working set. Per-step LDS = h exchange only.
// D[i=gatech][j=batchrow]: lane holds batchrow = l&15, gatech = 4*(l>>4)+j.
__global__ __launch_bounds__(512, 2)
void gru_main_kernel(const float* __restrict__ x,
                     const float* __restrict__ bhh_f,
                     const float* __restrict__ Wih_b, const float* __restrict__ bih_b,
                     const float* __restrict__ bhh_b,
                     const float* __restrict__ bp,
                     const float* __restrict__ gamma, const float* __restrict__ beta,
                     const unsigned char* __restrict__ ws,
                     float* __restrict__ out)
{
    // smem: loop: [0,16K) hbuf dbuf (2x8KB, XOR-swizzled)
    //       tail: [0,16K) lastb[16][512] bf16 ; [16K,32K) ybuf[16][256] f32
    __shared__ __align__(16) unsigned char smem[32768];
    __bf16* hbB = (__bf16*)smem;
    __bf16 (*lastb)[2 * HDIM] = (__bf16(*)[2 * HDIM])smem;
    float  (*ybuf)[HDIM]      = (float(*)[HDIM])(smem + 16384);

    const int tid = threadIdx.x, lane = tid & 63, w = tid >> 6;
    const int l15 = lane & 15, lq = lane >> 4;
    const int blockRow = blockIdx.x * 16;

    const b8* wsRZ = (const b8*)(ws + OFF_RZ);
    const b8* wsN  = (const b8*)(ws + OFF_N);
    const b8* wsWI = (const b8*)(ws + OFF_WIH);
    const b8* wsWP = (const b8*)(ws + OFF_WP);
    const b8* xB   = (const b8*)(ws + OFF_XB);

    const f32x4 zero4 = {0.f, 0.f, 0.f, 0.f};

    // zero h dbuf (16KB)
    *(f32x4*)(smem + tid * 16) = zero4;
    *(f32x4*)(smem + 8192 + tid * 16) = zero4;

    // ALL weight A-frags pinned in AGPRs: 48 Whh + 6 Wih = 216 a-regs
    b8 whr[2][8], whz[2][8], wnn[2][8], wir[2], wiz[2], win[2];
    {
        const int p = w;                     // wave owns 32ch: p = w (mtile pair)
        #pragma unroll
        for (int nt = 0; nt < 2; ++nt) {
            #pragma unroll
            for (int kt = 0; kt < 8; ++kt) {
                whr[nt][kt] = wsRZ[((p * 4 + 0 + nt) * 8 + kt) * 64 + lane];
                whz[nt][kt] = wsRZ[((p * 4 + 2 + nt) * 8 + kt) * 64 + lane];
                wnn[nt][kt] = wsN[((p * 2 + nt) * 8 + kt) * 64 + lane];
            }
            wir[nt] = wsWI[((p * 3 + 0) * 2 + nt) * 64 + lane];
            wiz[nt] = wsWI[((p * 3 + 1) * 2 + nt) * 64 + lane];
            win[nt] = wsWI[((p * 3 + 2) * 2 + nt) * 64 + lane];
        }
    }
    #pragma unroll
    for (int nt = 0; nt < 2; ++nt) {
        #pragma unroll
        for (int kt = 0; kt < 8; ++kt) {
            asm volatile("" : "+a"(whr[nt][kt]));
            asm volatile("" : "+a"(whz[nt][kt]));
            asm volatile("" : "+a"(wnn[nt][kt]));
        }
        asm volatile("" : "+a"(wir[nt]));
        asm volatile("" : "+a"(wiz[nt]));
        asm volatile("" : "+a"(win[nt]));
    }

    // bhh_n accumulator-init, pre-scaled by 2*log2e (C reg j <-> gatech 32w+16nt+4lq+j)
    float4 t0 = *(const float4*)&bhh_f[2 * HDIM + 32 * w + 0  + 4 * lq];
    float4 t1 = *(const float4*)&bhh_f[2 * HDIM + 32 * w + 16 + 4 * lq];
    f32x4 bnv0, bnv1;
    bnv0[0] = L2E2 * t0.x; bnv0[1] = L2E2 * t0.y; bnv0[2] = L2E2 * t0.z; bnv0[3] = L2E2 * t0.w;
    bnv1[0] = L2E2 * t1.x; bnv1[1] = L2E2 * t1.y; bnv1[2] = L2E2 * t1.z; bnv1[3] = L2E2 * t1.w;

    // constant part of x B-frag: k=8 -> 1.0 (bias multiplier)
    b8 xc;
    #pragma unroll
    for (int e = 0; e < 8; ++e) xc[e] = (__bf16)0.0f;
    if (lq == 1) xc[0] = (__bf16)1.0f;

    // h master state in regs: (row=l15, ch=32w+16nt+4lq+j)
    f32x4 h0 = zero4, h1 = zero4;

    const int kswz = (8 * lq) ^ ((l15 & 7) << 3);     // B-read swizzle base
    const int wswz = (l15 & 7) << 3;                  // write swizzle
    const b8* xRow = xB + (blockRow + l15) * WDIM;

    // prefetch x for t=0
    b8 xf = xc;
    if (lane < 16) xf = xRow[0];

    __syncthreads();

    int cur = 0;
    for (int t = 0; t < WDIM; ++t) {
        // prefetch next step's x early (L2 latency hidden under MFMA)
        b8 xn = xc;
        if (lane < 16) xn = xRow[(t + 1) & 127];

        const __bf16* hc = hbB + cur * 4096 + l15 * 256;

        f32x4 aR0 = zero4, aR1 = zero4;
        f32x4 aZ0 = zero4, aZ1 = zero4;
        f32x4 aNH0 = bnv0, aNH1 = bnv1;

        #pragma unroll
        for (int kt = 0; kt < 8; ++kt) {
            b8 hfrag = *(const b8*)(hc + ((kt << 5) ^ kswz));
            aR0  = MFMA(whr[0][kt], hfrag, aR0);
            aR1  = MFMA(whr[1][kt], hfrag, aR1);
            aZ0  = MFMA(whz[0][kt], hfrag, aZ0);
            aZ1  = MFMA(whz[1][kt], hfrag, aZ1);
            aNH0 = MFMA(wnn[0][kt], hfrag, aNH0);
            aNH1 = MFMA(wnn[1][kt], hfrag, aNH1);
        }
        // x-part (+ r,z biases via k=8 slot)
        aR0 = MFMA(wir[0], xf, aR0);
        aR1 = MFMA(wir[1], xf, aR1);
        aZ0 = MFMA(wiz[0], xf, aZ0);
        aZ1 = MFMA(wiz[1], xf, aZ1);
        f32x4 aNX0 = MFMA(win[0], xf, zero4);
        f32x4 aNX1 = MFMA(win[1], xf, zero4);

        // gate fusion: weights pre-scaled by log2e -> raw exp2 (v_exp_f32)
        __bf16* hn = hbB + (cur ^ 1) * 4096;
        b4 v0, v1;
        #pragma unroll
        for (int j = 0; j < 4; ++j) {
            float r = __builtin_amdgcn_rcpf(1.0f + __builtin_amdgcn_exp2f(-aR0[j]));
            float z = __builtin_amdgcn_rcpf(1.0f + __builtin_amdgcn_exp2f(-aZ0[j]));
            float u = fmaf(r, aNH0[j], aNX0[j]);
            float n = fmaf(-2.0f, __builtin_amdgcn_rcpf(1.0f + __builtin_amdgcn_exp2f(u)), 1.0f);
            float hv = n + z * (h0[j] - n);
            h0[j] = hv; v0[j] = (__bf16)hv;

            r = __builtin_amdgcn_rcpf(1.0f + __builtin_amdgcn_exp2f(-aR1[j]));
            z = __builtin_amdgcn_rcpf(1.0f + __builtin_amdgcn_exp2f(-aZ1[j]));
            u = fmaf(r, aNH1[j], aNX1[j]);
            n = fmaf(-2.0f, __builtin_amdgcn_rcpf(1.0f + __builtin_amdgcn_exp2f(u)), 1.0f);
            hv = n + z * (h1[j] - n);
            h1[j] = hv; v1[j] = (__bf16)hv;
        }
        *(b4*)(hn + l15 * 256 + ((32 * w + 0  + 4 * lq) ^ wswz)) = v0;
        *(b4*)(hn + l15 * 256 + ((32 * w + 16 + 4 * lq) ^ wswz)) = v1;

        xf = xn;
        cur ^= 1;
        __syncthreads();
    }

    // ---- write forward h (f32 regs) into lastb cols [0,256) ----
    {
        b4 v0, v1;
        #pragma unroll
        for (int j = 0; j < 4; ++j) { v0[j] = (__bf16)h0[j]; v1[j] = (__bf16)h1[j]; }
        *(b4*)(&lastb[l15][0] + ((32 * w + 0  + 4 * lq) ^ wswz)) = v0;
        *(b4*)(&lastb[l15][0] + ((32 * w + 16 + 4 * lq) ^ wswz)) = v1;
    }

    // ---- backward cell (h0=0, one step on x[:,127,:]) -> lastb cols [256,512) ----
    {
        const int trow = tid >> 5;           // 0..15
        const int cb = tid & 31;
        const float4* xr = (const float4*)(x + (blockRow + trow) * WDIM * FDIM + 127 * FDIM);
        float4 xv0 = xr[0], xv1 = xr[1];
        const float4* wb = (const float4*)Wih_b;
        #pragma unroll
        for (int jj = 0; jj < 8; ++jj) {
            int ch = cb + 32 * jj;
            float4 a0 = wb[ch * 2],               a1 = wb[ch * 2 + 1];
            float4 b0 = wb[(HDIM + ch) * 2],      b1 = wb[(HDIM + ch) * 2 + 1];
            float4 c0v = wb[(2 * HDIM + ch) * 2], c1 = wb[(2 * HDIM + ch) * 2 + 1];
            float ir = bih_b[ch]
                + xv0.x * a0.x + xv0.y * a0.y + xv0.z * a0.z + xv0.w * a0.w
                + xv1.x * a1.x + xv1.y * a1.y + xv1.z * a1.z + xv1.w * a1.w;
            float iz = bih_b[HDIM + ch]
                + xv0.x * b0.x + xv0.y * b0.y + xv0.z * b0.z + xv0.w * b0.w
                + xv1.x * b1.x + xv1.y * b1.y + xv1.z * b1.z + xv1.w * b1.w;
            float inn = bih_b[2 * HDIM + ch]
                + xv0.x * c0v.x + xv0.y * c0v.y + xv0.z * c0v.z + xv0.w * c0v.w
                + xv1.x * c1.x + xv1.y * c1.y + xv1.z * c1.z + xv1.w * c1.w;
            float r = sig_(ir + bhh_b[ch]);
            float z = sig_(iz + bhh_b[HDIM + ch]);
            float n = tanh_(fmaf(r, bhh_b[2 * HDIM + ch], inn));
            float hbw = (1.0f - z) * n;
            int c2 = HDIM + ch;
            lastb[trow][c2 ^ ((trow & 7) << 3)] = (__bf16)hbw;
        }
    }
    __syncthreads();

    // ---- projection: y = gelu(last @ Wp^T + bp); wave w -> cols [32w,32w+32) ----
    {
        f32x4 pacc[2];
        #pragma unroll
        for (int nt = 0; nt < 2; ++nt) {
            int col = 32 * w + nt * 16 + l15;
            float b = bp[col];
            pacc[nt][0] = b; pacc[nt][1] = b; pacc[nt][2] = b; pacc[nt][3] = b;
        }
        #pragma unroll
        for (int kt = 0; kt < 16; ++kt) {
            int c = (kt * 32 + lq * 8) ^ ((l15 & 7) << 3);
            b8 a = *(const b8*)&lastb[l15][c];
            #pragma unroll
            for (int nt = 0; nt < 2; ++nt)
                pacc[nt] = MFMA(a, wsWP[((2 * w + nt) * 16 + kt) * 64 + lane], pacc[nt]);
        }
        #pragma unroll
        for (int nt = 0; nt < 2; ++nt) {
            int col = 32 * w + nt * 16 + l15;
            #pragma unroll
            for (int j = 0; j < 4; ++j) {
                int row = lq * 4 + j;
                float v = pacc[nt][j];
                ybuf[row][col] = 0.5f * v * (1.0f + erff(v * 0.70710678118f));
            }
        }
    }
    __syncthreads();

    // ---- LayerNorm: one wave per 2 rows ----
    #pragma unroll
    for (int rr = 0; rr < 2; ++rr) {
        int row = 2 * w + rr;
        float v[4];
        float s = 0.0f, sq = 0.0f;
        #pragma unroll
        for (int m = 0; m < 4; ++m) {
            v[m] = ybuf[row][lane + 64 * m];
            s += v[m];
            sq += v[m] * v[m];
        }
        #pragma unroll
        for (int off = 32; off >= 1; off >>= 1) {
            s  += __shfl_xor(s, off, 64);
            sq += __shfl_xor(sq, off, 64);
        }
        float mu = s * (1.0f / 256.0f);
        float var = sq * (1.0f / 256.0f) - mu * mu;
        float rs = rsqrtf(var + 1e-5f);
        float* orow = out + (blockRow + row) * HDIM;
        #pragma unroll
        for (int m = 0; m < 4; ++m) {
            int cc = lane + 64 * m;
            orow[cc] = (v[m] - mu) * rs * gamma[cc] + beta[cc];
        }
    }
}

extern "C" void kernel_launch(void* const* d_in, const int* in_sizes, int n_in,
                              void* d_out, int out_size, void* d_ws, size_t ws_size,
                              hipStream_t stream)
{
    const float* x     = (const float*)d_in[0];
    const float* Wih_f = (const float*)d_in[1];
    const float* Whh_f = (const float*)d_in[2];
    const float* bih_f = (const float*)d_in[3];
    const float* bhh_f = (const float*)d_in[4];
    const float* Wih_b = (const float*)d_in[5];
    // d_in[6] = Whh_b unused: h0=0 so gh_b = bhh_b exactly
    const float* bih_b = (const float*)d_in[7];
    const float* bhh_b = (const float*)d_in[8];
    const float* Wp    = (const float*)d_in[9];
    const float* bp    = (const float*)d_in[10];
    const float* gamma = (const float*)d_in[11];
    const float* beta  = (const float*)d_in[12];
    float* out = (float*)d_out;
    unsigned char* ws = (unsigned char*)d_ws;

    const int packItems = 16384 + 8192 + 3072 + 16384 + 262144;   // 306176
    hipLaunchKernelGGL(pack_kernel, dim3((packItems + 255) / 256), dim3(256), 0, stream,
                       x, Wih_f, Whh_f, bih_f, bhh_f, Wp, ws);
    hipLaunchKernelGGL(gru_main_kernel, dim3(BDIM / 16), dim3(512), 0, stream,
                       x, bhh_f, Wih_b, bih_b, bhh_b, bp, gamma, beta, ws, out);
}

// Round 9
// 327.642 us; speedup vs baseline: 1.6128x; 1.6128x over previous
//
#include <hip/hip_runtime.h>
#include <hip/hip_bf16.h>

#define BDIM 2048
#define WDIM 128
#define FDIM 8
#define HDIM 256

typedef __bf16 b8 __attribute__((ext_vector_type(8)));
typedef __bf16 b4 __attribute__((ext_vector_type(4)));
typedef float f32x4 __attribute__((ext_vector_type(4)));

#define L2E  1.44269504088896f
#define L2E2 2.88539008177793f

// workspace layout (bytes), all 16B aligned
#define OFF_RZ  0                 // 256 frags * 1KB (r,z Whh A-frags, pre-scaled by log2e)
#define OFF_N   262144            // 128 frags * 1KB (n Whh A-frags, pre-scaled by 2*log2e)
#define OFF_WIH 393216            // 48 frags * 1KB  (Wih A-frags + bias in k=8, pre-scaled)
#define OFF_WP  442368            // 256 frags * 1KB (Wp B-frags, unscaled)
#define OFF_XB  704512            // 2048*128*8 bf16 = 4194304
// total 4,898,816 B

// dynamic LDS: [0,16K) h dbuf (2x8KB) ; [16K,64K) Wih frags (48 x 1KB)
// tail overlay: [0,16K) lastb[16][512] bf16 ; [16K,32K) ybuf[16][256] f32
#define SMEM_BYTES 65536

#define MFMA(a,b,c) __builtin_amdgcn_mfma_f32_16x16x32_bf16((a),(b),(c),0,0,0)

static __device__ __forceinline__ float sig_(float v) {      // tail only (unscaled)
    return __builtin_amdgcn_rcpf(1.0f + __expf(-v));
}
static __device__ __forceinline__ float tanh_(float v) {     // tail only (unscaled)
    return fmaf(-2.0f, __builtin_amdgcn_rcpf(1.0f + __expf(2.0f * v)), 1.0f);
}

// ---------------- pack: weights/x -> bf16 MFMA fragments (log2e pre-scaled) ----------------
// A-frag (16x16x32): lane l holds A[i = l&15][k = kt*32 + (l>>4)*8 + e]
// B-frag:            lane l holds B[k = kt*32 + (l>>4)*8 + e][j = l&15]
__global__ void pack_kernel(const float* __restrict__ x,
                            const float* __restrict__ Wih_f,
                            const float* __restrict__ Whh_f,
                            const float* __restrict__ bih_f,
                            const float* __restrict__ bhh_f,
                            const float* __restrict__ Wp,
                            unsigned char* __restrict__ ws)
{
    int idx = blockIdx.x * 256 + threadIdx.x;
    if (idx < 16384) {                       // r,z Whh A-frags: f = (p*4+2g+nt)*8+kt
        int l = idx & 63, f = idx >> 6;
        int kt = f & 7, nt = (f >> 3) & 1, g = (f >> 4) & 1, p = f >> 5;
        int gch = g * HDIM + 32 * p + 16 * nt + (l & 15);
        int kb = kt * 32 + (l >> 4) * 8;
        b8 v;
        #pragma unroll
        for (int e = 0; e < 8; ++e) v[e] = (__bf16)(L2E * Whh_f[gch * HDIM + kb + e]);
        ((b8*)(ws + OFF_RZ))[idx] = v;
    } else if (idx < 24576) {                // n Whh A-frags: f = mtile*8+kt  (x 2*log2e)
        int j = idx - 16384;
        int l = j & 63, f = j >> 6;
        int kt = f & 7, m = f >> 3;
        int gch = 2 * HDIM + 16 * m + (l & 15);
        int kb = kt * 32 + (l >> 4) * 8;
        b8 v;
        #pragma unroll
        for (int e = 0; e < 8; ++e) v[e] = (__bf16)(L2E2 * Whh_f[gch * HDIM + kb + e]);
        ((b8*)(ws + OFF_N))[j] = v;
    } else if (idx < 27648) {                // Wih A-frags: f = (p*3+g)*2+nt (bias at k=8)
        int j = idx - 24576;
        int l = j & 63, f = j >> 6;
        int nt = f & 1, q = f >> 1, g = q % 3, p = q / 3;
        int gch = g * HDIM + 32 * p + 16 * nt + (l & 15);
        int lq = l >> 4;
        float sc = (g == 2) ? L2E2 : L2E;
        b8 v;
        #pragma unroll
        for (int e = 0; e < 8; ++e) v[e] = (__bf16)0.0f;
        if (lq == 0) {
            #pragma unroll
            for (int e = 0; e < 8; ++e) v[e] = (__bf16)(sc * Wih_f[gch * FDIM + e]);
        } else if (lq == 1) {
            float b = (g == 2) ? (L2E2 * bih_f[gch]) : (L2E * (bih_f[gch] + bhh_f[gch]));
            v[0] = (__bf16)b;                // pairs with 1.0 in x B-frag k=8
        }
        ((b8*)(ws + OFF_WIH))[j] = v;
    } else if (idx < 44032) {                // Wp B-frags (unscaled)
        int j = idx - 27648;
        int l = j & 63, nk = j >> 6;
        int NT = nk >> 4, kt = nk & 15;
        int col = NT * 16 + (l & 15);
        int kb = kt * 32 + (l >> 4) * 8;
        b8 v;
        #pragma unroll
        for (int e = 0; e < 8; ++e) v[e] = (__bf16)Wp[col * (2 * HDIM) + kb + e];
        ((b8*)(ws + OFF_WP))[j] = v;
    } else if (idx < 44032 + 262144) {       // x -> bf16 rows [row][t][8]
        int j = idx - 44032;
        const float* src = x + j * 8;
        b8 v;
        #pragma unroll
        for (int e = 0; e < 8; ++e) v[e] = (__bf16)src[e];
        ((b8*)(ws + OFF_XB))[j] = v;
    }
}

// ---------------- fused GRU: 128 blocks x 256 threads (4 waves), 16 rows/block ----------------
// 1 wave/SIMD -> 512 regs/wave (256 VGPR + 256 AGPR). Wave w owns channels [64w, 64w+64)
// = mtiles 4w..4w+3 of each gate. ALL Whh in regs: whr (32 frags) "+v", whz+wnn (64) "+a".
// Wih in LDS (one-time stage). Per-step LDS = h exchange + 12 Wih reads.
// D[i=gatech][j=batchrow]: lane holds batchrow = l&15, gatech = 16*mt + 4*(l>>4)+j.
__global__ __launch_bounds__(256, 1)
void gru_main_kernel(const float* __restrict__ x,
                     const float* __restrict__ bhh_f,
                     const float* __restrict__ Wih_b, const float* __restrict__ bih_b,
                     const float* __restrict__ bhh_b,
                     const float* __restrict__ bp,
                     const float* __restrict__ gamma, const float* __restrict__ beta,
                     const unsigned char* __restrict__ ws,
                     float* __restrict__ out)
{
    extern __shared__ __align__(16) unsigned char smem[];
    __bf16* hbB = (__bf16*)smem;                            // [0,16K) h dbuf 2x8KB
    b8* wihL = (b8*)(smem + 16384);                         // [16K,64K) 48 Wih frags
    __bf16 (*lastb)[2 * HDIM] = (__bf16(*)[2 * HDIM])smem;  // tail overlay [0,16K)
    float  (*ybuf)[HDIM]      = (float(*)[HDIM])(smem + 16384); // [16K,32K)

    const int tid = threadIdx.x, lane = tid & 63, w = tid >> 6;   // w 0..3
    const int l15 = lane & 15, lq = lane >> 4;
    const int blockRow = blockIdx.x * 16;

    const b8* wsRZ = (const b8*)(ws + OFF_RZ);
    const b8* wsN  = (const b8*)(ws + OFF_N);
    const b8* wsWI = (const b8*)(ws + OFF_WIH);
    const b8* wsWP = (const b8*)(ws + OFF_WP);
    const b8* xB   = (const b8*)(ws + OFF_XB);

    const f32x4 zero4 = {0.f, 0.f, 0.f, 0.f};

    // zero h dbuf (16KB): 256 threads x 16B x 4
    #pragma unroll
    for (int k = 0; k < 4; ++k)
        *(f32x4*)(smem + k * 4096 + tid * 16) = zero4;

    // stage all 48 Wih frags into LDS (48KB one-time)
    for (int i = tid; i < 3072; i += 256) wihL[i] = wsWI[i];

    // ALL Whh A-frags in regs: whr 32 frags (128 VGPR), whz+wnn 64 frags (256 AGPR)
    b8 whr[4][8], whz[4][8], wnn[4][8];
    #pragma unroll
    for (int mt = 0; mt < 4; ++mt) {
        const int p = 2 * w + (mt >> 1), nt = mt & 1;
        #pragma unroll
        for (int kt = 0; kt < 8; ++kt) {
            whr[mt][kt] = wsRZ[((p * 4 + 0 + nt) * 8 + kt) * 64 + lane];
            whz[mt][kt] = wsRZ[((p * 4 + 2 + nt) * 8 + kt) * 64 + lane];
            wnn[mt][kt] = wsN[((4 * w + mt) * 8 + kt) * 64 + lane];
        }
    }
    #pragma unroll
    for (int mt = 0; mt < 4; ++mt) {
        #pragma unroll
        for (int kt = 0; kt < 8; ++kt) {
            asm volatile("" : "+v"(whr[mt][kt]));
            asm volatile("" : "+a"(whz[mt][kt]));
            asm volatile("" : "+a"(wnn[mt][kt]));
        }
    }

    // bhh_n init values, pre-scaled (C reg j <-> gatech 64w+16mt+4lq+j)
    f32x4 bnv[4];
    #pragma unroll
    for (int mt = 0; mt < 4; ++mt) {
        float4 t = *(const float4*)&bhh_f[2 * HDIM + 64 * w + 16 * mt + 4 * lq];
        bnv[mt][0] = L2E2 * t.x; bnv[mt][1] = L2E2 * t.y;
        bnv[mt][2] = L2E2 * t.z; bnv[mt][3] = L2E2 * t.w;
    }

    // constant part of x B-frag: k=8 -> 1.0 (bias multiplier)
    b8 xc;
    #pragma unroll
    for (int e = 0; e < 8; ++e) xc[e] = (__bf16)0.0f;
    if (lq == 1) xc[0] = (__bf16)1.0f;

    // h master state in regs: h[mt][j] for (row=l15, ch=64w+16mt+4lq+j)
    f32x4 h[4];
    #pragma unroll
    for (int mt = 0; mt < 4; ++mt) h[mt] = zero4;

    const int kswz = (8 * lq) ^ ((l15 & 7) << 3);     // B-read swizzle base
    const int wswz = (l15 & 7) << 3;                  // write swizzle
    const b8* xRow = xB + (blockRow + l15) * WDIM;
    // this wave's 12 Wih frag pointers (LDS)
    const int fbase0 = ((2 * w + 0) * 3) * 2;         // mtiles 0,1: frags fbase0 + g*2 + nt
    const int fbase1 = ((2 * w + 1) * 3) * 2;         // mtiles 2,3

    __syncthreads();

    int cur = 0;
    for (int t = 0; t < WDIM; ++t) {
        // x B-frag (L2; latency hidden under kt loop)
        b8 xf = xc;
        if (lane < 16) xf = xRow[t];

        f32x4 aR[4], aZ[4], aNH[4];
        #pragma unroll
        for (int mt = 0; mt < 4; ++mt) { aR[mt] = zero4; aZ[mt] = zero4; aNH[mt] = bnv[mt]; }

        const __bf16* hc = hbB + cur * 4096 + l15 * 256;
        #pragma unroll
        for (int kt = 0; kt < 8; ++kt) {
            b8 hfrag = *(const b8*)(hc + ((kt << 5) ^ kswz));
            #pragma unroll
            for (int mt = 0; mt < 4; ++mt) {
                aR[mt]  = MFMA(whr[mt][kt], hfrag, aR[mt]);
                aZ[mt]  = MFMA(whz[mt][kt], hfrag, aZ[mt]);
                aNH[mt] = MFMA(wnn[mt][kt], hfrag, aNH[mt]);
            }
        }

        // gate phase, per mtile: x-part MFMAs (Wih from LDS) + fusion + h write
        __bf16* hn = hbB + (cur ^ 1) * 4096;
        #pragma unroll
        for (int mt = 0; mt < 4; ++mt) {
            const int fb = (mt < 2 ? fbase0 : fbase1) + (mt & 1);
            b8 wr = wihL[(fb + 0) * 64 + lane];
            b8 wz = wihL[(fb + 2) * 64 + lane];
            b8 wn = wihL[(fb + 4) * 64 + lane];
            aR[mt] = MFMA(wr, xf, aR[mt]);
            aZ[mt] = MFMA(wz, xf, aZ[mt]);
            f32x4 aNX = MFMA(wn, xf, zero4);

            b4 v0;
            #pragma unroll
            for (int j = 0; j < 4; ++j) {
                float r = __builtin_amdgcn_rcpf(1.0f + __builtin_amdgcn_exp2f(-aR[mt][j]));
                float z = __builtin_amdgcn_rcpf(1.0f + __builtin_amdgcn_exp2f(-aZ[mt][j]));
                float u = fmaf(r, aNH[mt][j], aNX[j]);
                float n = fmaf(-2.0f, __builtin_amdgcn_rcpf(1.0f + __builtin_amdgcn_exp2f(u)), 1.0f);
                float hv = n + z * (h[mt][j] - n);
                h[mt][j] = hv; v0[j] = (__bf16)hv;
            }
            *(b4*)(hn + l15 * 256 + ((64 * w + 16 * mt + 4 * lq) ^ wswz)) = v0;
        }

        cur ^= 1;
        __syncthreads();
    }

    // ---- write forward h into lastb cols [0,256) ----
    #pragma unroll
    for (int mt = 0; mt < 4; ++mt) {
        b4 v0;
        #pragma unroll
        for (int j = 0; j < 4; ++j) v0[j] = (__bf16)h[mt][j];
        *(b4*)(&lastb[l15][0] + ((64 * w + 16 * mt + 4 * lq) ^ wswz)) = v0;
    }

    // ---- backward cell (h0=0, one step on x[:,127,:]) -> lastb cols [256,512) ----
    {
        const int trow = tid >> 4;           // 0..15
        const int cb = tid & 15;
        const float4* xr = (const float4*)(x + (blockRow + trow) * WDIM * FDIM + 127 * FDIM);
        float4 xv0 = xr[0], xv1 = xr[1];
        const float4* wb = (const float4*)Wih_b;
        #pragma unroll
        for (int jj = 0; jj < 16; ++jj) {
            int ch = cb + 16 * jj;
            float4 a0 = wb[ch * 2],               a1 = wb[ch * 2 + 1];
            float4 b0 = wb[(HDIM + ch) * 2],      b1 = wb[(HDIM + ch) * 2 + 1];
            float4 c0v = wb[(2 * HDIM + ch) * 2], c1 = wb[(2 * HDIM + ch) * 2 + 1];
            float ir = bih_b[ch]
                + xv0.x * a0.x + xv0.y * a0.y + xv0.z * a0.z + xv0.w * a0.w
                + xv1.x * a1.x + xv1.y * a1.y + xv1.z * a1.z + xv1.w * a1.w;
            float iz = bih_b[HDIM + ch]
                + xv0.x * b0.x + xv0.y * b0.y + xv0.z * b0.z + xv0.w * b0.w
                + xv1.x * b1.x + xv1.y * b1.y + xv1.z * b1.z + xv1.w * b1.w;
            float inn = bih_b[2 * HDIM + ch]
                + xv0.x * c0v.x + xv0.y * c0v.y + xv0.z * c0v.z + xv0.w * c0v.w
                + xv1.x * c1.x + xv1.y * c1.y + xv1.z * c1.z + xv1.w * c1.w;
            float r = sig_(ir + bhh_b[ch]);
            float z = sig_(iz + bhh_b[HDIM + ch]);
            float n = tanh_(fmaf(r, bhh_b[2 * HDIM + ch], inn));
            float hbw = (1.0f - z) * n;
            int c2 = HDIM + ch;
            lastb[trow][c2 ^ ((trow & 7) << 3)] = (__bf16)hbw;
        }
    }
    __syncthreads();

    // ---- projection: y = gelu(last @ Wp^T + bp); wave w -> cols [64w, 64w+64) ----
    {
        f32x4 pacc[4];
        #pragma unroll
        for (int ct = 0; ct < 4; ++ct) {
            int col = 64 * w + 16 * ct + l15;
            float b = bp[col];
            pacc[ct][0] = b; pacc[ct][1] = b; pacc[ct][2] = b; pacc[ct][3] = b;
        }
        #pragma unroll
        for (int kt = 0; kt < 16; ++kt) {
            int c = (kt * 32 + lq * 8) ^ ((l15 & 7) << 3);
            b8 a = *(const b8*)&lastb[l15][c];
            #pragma unroll
            for (int ct = 0; ct < 4; ++ct)
                pacc[ct] = MFMA(a, wsWP[((4 * w + ct) * 16 + kt) * 64 + lane], pacc[ct]);
        }
        #pragma unroll
        for (int ct = 0; ct < 4; ++ct) {
            int col = 64 * w + 16 * ct + l15;
            #pragma unroll
            for (int j = 0; j < 4; ++j) {
                int row = lq * 4 + j;
                float v = pacc[ct][j];
                ybuf[row][col] = 0.5f * v * (1.0f + erff(v * 0.70710678118f));
            }
        }
    }
    __syncthreads();

    // ---- LayerNorm: 4 waves x 4 rows each ----
    #pragma unroll
    for (int rr = 0; rr < 4; ++rr) {
        int row = 4 * w + rr;
        float v[4];
        float s = 0.0f, sq = 0.0f;
        #pragma unroll
        for (int m = 0; m < 4; ++m) {
            v[m] = ybuf[row][lane + 64 * m];
            s += v[m];
            sq += v[m] * v[m];
        }
        #pragma unroll
        for (int off = 32; off >= 1; off >>= 1) {
            s  += __shfl_xor(s, off, 64);
            sq += __shfl_xor(sq, off, 64);
        }
        float mu = s * (1.0f / 256.0f);
        float var = sq * (1.0f / 256.0f) - mu * mu;
        float rs = rsqrtf(var + 1e-5f);
        float* orow = out + (blockRow + row) * HDIM;
        #pragma unroll
        for (int m = 0; m < 4; ++m) {
            int cc = lane + 64 * m;
            orow[cc] = (v[m] - mu) * rs * gamma[cc] + beta[cc];
        }
    }
}

extern "C" void kernel_launch(void* const* d_in, const int* in_sizes, int n_in,
                              void* d_out, int out_size, void* d_ws, size_t ws_size,
                              hipStream_t stream)
{
    const float* x     = (const float*)d_in[0];
    const float* Wih_f = (const float*)d_in[1];
    const float* Whh_f = (const float*)d_in[2];
    const float* bih_f = (const float*)d_in[3];
    const float* bhh_f = (const float*)d_in[4];
    const float* Wih_b = (const float*)d_in[5];
    // d_in[6] = Whh_b unused: h0=0 so gh_b = bhh_b exactly
    const float* bih_b = (const float*)d_in[7];
    const float* bhh_b = (const float*)d_in[8];
    const float* Wp    = (const float*)d_in[9];
    const float* bp    = (const float*)d_in[10];
    const float* gamma = (const float*)d_in[11];
    const float* beta  = (const float*)d_in[12];
    float* out = (float*)d_out;
    unsigned char* ws = (unsigned char*)d_ws;

    // allow 64KB dynamic LDS (host-side attribute, graph-capture safe)
    hipFuncSetAttribute((const void*)gru_main_kernel,
                        hipFuncAttributeMaxDynamicSharedMemorySize, SMEM_BYTES);

    const int packItems = 16384 + 8192 + 3072 + 16384 + 262144;   // 306176
    hipLaunchKernelGGL(pack_kernel, dim3((packItems + 255) / 256), dim3(256), 0, stream,
                       x, Wih_f, Whh_f, bih_f, bhh_f, Wp, ws);
    hipLaunchKernelGGL(gru_main_kernel, dim3(BDIM / 16), dim3(256), SMEM_BYTES, stream,
                       x, bhh_f, Wih_b, bih_b, bhh_b, bp, gamma, beta, ws, out);
}

// Round 10
// 196.694 us; speedup vs baseline: 2.6865x; 1.6657x over previous
//
#include <hip/hip_runtime.h>
#include <hip/hip_bf16.h>

#define BDIM 2048
#define WDIM 128
#define FDIM 8
#define HDIM 256

typedef __bf16 b8 __attribute__((ext_vector_type(8)));
typedef __bf16 b4 __attribute__((ext_vector_type(4)));
typedef float f32x4 __attribute__((ext_vector_type(4)));

#define L2E  1.44269504088896f
#define L2E2 2.88539008177793f

// workspace layout (bytes), all 16B aligned
#define OFF_RZ  0                 // 256 frags * 1KB (r,z Whh A-frags, pre-scaled by -log2e)
#define OFF_N   262144            // 128 frags * 1KB (n Whh A-frags -> LDS, pre-scaled by 2*log2e)
#define OFF_WIH 393216            // 48 frags * 1KB  (Wih A-frags + bias in k=8, pre-scaled)
#define OFF_WP  442368            // 256 frags * 1KB (Wp B-frags, unscaled)
#define OFF_XB  704512            // 2048*128*8 bf16 = 4194304
// total 4,898,816 B

// dynamic LDS layout (bytes): [0,16K) h dbuf (2x8KB) ; [16K,144K) n-gate frags
// tail overlay: [0,16K) lastb[16][512] bf16 ; [16K,32K) ybuf[16][256] f32
#define SMEM_BYTES 147456

#define MFMA(a,b,c) __builtin_amdgcn_mfma_f32_16x16x32_bf16((a),(b),(c),0,0,0)

static __device__ __forceinline__ float sig_(float v) {      // tail only (unscaled)
    return __builtin_amdgcn_rcpf(1.0f + __expf(-v));
}
static __device__ __forceinline__ float tanh_(float v) {     // tail only (unscaled)
    return fmaf(-2.0f, __builtin_amdgcn_rcpf(1.0f + __expf(2.0f * v)), 1.0f);
}

// ---------------- pack: weights/x -> bf16 MFMA fragments (log2e pre-scaled) ----------------
// A-frag (16x16x32): lane l holds A[i = l&15][k = kt*32 + (l>>4)*8 + e]
// B-frag:            lane l holds B[k = kt*32 + (l>>4)*8 + e][j = l&15]
__global__ void pack_kernel(const float* __restrict__ x,
                            const float* __restrict__ Wih_f,
                            const float* __restrict__ Whh_f,
                            const float* __restrict__ bih_f,
                            const float* __restrict__ bhh_f,
                            const float* __restrict__ Wp,
                            unsigned char* __restrict__ ws)
{
    int idx = blockIdx.x * 256 + threadIdx.x;
    if (idx < 16384) {                       // r,z Whh A-frags: f = (w*4+2g+nt)*8+kt, x(-log2e)
        int l = idx & 63, f = idx >> 6;
        int kt = f & 7, nt = (f >> 3) & 1, g = (f >> 4) & 1, w = f >> 5;
        int gch = g * HDIM + 32 * w + 16 * nt + (l & 15);
        int kb = kt * 32 + (l >> 4) * 8;
        b8 v;
        #pragma unroll
        for (int e = 0; e < 8; ++e) v[e] = (__bf16)(-L2E * Whh_f[gch * HDIM + kb + e]);
        ((b8*)(ws + OFF_RZ))[idx] = v;
    } else if (idx < 24576) {                // n Whh A-frags: f = (w*2+nt)*8+kt, x(2*log2e)
        int j = idx - 16384;
        int l = j & 63, f = j >> 6;
        int kt = f & 7, nt = (f >> 3) & 1, w = f >> 4;
        int gch = 2 * HDIM + 32 * w + 16 * nt + (l & 15);
        int kb = kt * 32 + (l >> 4) * 8;
        b8 v;
        #pragma unroll
        for (int e = 0; e < 8; ++e) v[e] = (__bf16)(L2E2 * Whh_f[gch * HDIM + kb + e]);
        ((b8*)(ws + OFF_N))[j] = v;
    } else if (idx < 27648) {                // Wih A-frags (K=8 real, bias at k=8), pre-scaled
        int j = idx - 24576;
        int l = j & 63, f = j >> 6;
        int nt = f & 1, q = f >> 1, g = q % 3, w = q / 3;
        int gch = g * HDIM + 32 * w + 16 * nt + (l & 15);
        int lq = l >> 4;
        float sc = (g == 2) ? L2E2 : -L2E;
        b8 v;
        #pragma unroll
        for (int e = 0; e < 8; ++e) v[e] = (__bf16)0.0f;
        if (lq == 0) {
            #pragma unroll
            for (int e = 0; e < 8; ++e) v[e] = (__bf16)(sc * Wih_f[gch * FDIM + e]);
        } else if (lq == 1) {
            float b = (g == 2) ? (L2E2 * bih_f[gch]) : (-L2E * (bih_f[gch] + bhh_f[gch]));
            v[0] = (__bf16)b;                // pairs with 1.0 in x B-frag k=8
        }
        ((b8*)(ws + OFF_WIH))[j] = v;
    } else if (idx < 44032) {                // Wp B-frags (unscaled)
        int j = idx - 27648;
        int l = j & 63, nk = j >> 6;
        int NT = nk >> 4, kt = nk & 15;
        int col = NT * 16 + (l & 15);
        int kb = kt * 32 + (l >> 4) * 8;
        b8 v;
        #pragma unroll
        for (int e = 0; e < 8; ++e) v[e] = (__bf16)Wp[col * (2 * HDIM) + kb + e];
        ((b8*)(ws + OFF_WP))[j] = v;
    } else if (idx < 44032 + 262144) {       // x -> bf16 rows [row][t][8]
        int j = idx - 44032;
        const float* src = x + j * 8;
        b8 v;
        #pragma unroll
        for (int e = 0; e < 8; ++e) v[e] = (__bf16)src[e];
        ((b8*)(ws + OFF_XB))[j] = v;
    }
}

// ---------------- fused GRU (transposed MFMA) — round-4 geometry ----------------
// 128 blocks x 512 threads (8 waves). Block owns 16 batch rows.
// Wave w owns gate channels [32w, 32w+32) of r, z, n (as M-tiles).
// r,z Whh + Wih pinned in regs/AGPRs; n Whh in LDS; h master state in VGPRs.
// x-part MFMAs issued at TOP of each step (fills post-barrier ds_read shadow).
// D[i=gatech][j=batchrow]: lane holds batchrow = l&15, gatech = 4*(l>>4)+j.
__global__ __launch_bounds__(512, 2)
void gru_main_kernel(const float* __restrict__ x,
                     const float* __restrict__ bhh_f,
                     const float* __restrict__ Wih_b, const float* __restrict__ bih_b,
                     const float* __restrict__ bhh_b,
                     const float* __restrict__ bp,
                     const float* __restrict__ gamma, const float* __restrict__ beta,
                     const unsigned char* __restrict__ ws,
                     float* __restrict__ out)
{
    extern __shared__ __align__(16) unsigned char smem[];
    __bf16* hbB = (__bf16*)smem;                            // [0,16K) h dbuf
    b8* nlds = (b8*)(smem + 16384);                         // [16K,144K) n frags
    __bf16 (*lastb)[2 * HDIM] = (__bf16(*)[2 * HDIM])smem;  // tail overlay
    float  (*ybuf)[HDIM]      = (float(*)[HDIM])(smem + 16384);

    const int tid = threadIdx.x, lane = tid & 63, w = tid >> 6;
    const int l15 = lane & 15, lq = lane >> 4;
    const int blockRow = blockIdx.x * 16;

    const b8* wsRZ = (const b8*)(ws + OFF_RZ);
    const b8* wsN  = (const b8*)(ws + OFF_N);
    const b8* wsWI = (const b8*)(ws + OFF_WIH);
    const b8* wsWP = (const b8*)(ws + OFF_WP);
    const b8* xB   = (const b8*)(ws + OFF_XB);

    const f32x4 zero4 = {0.f, 0.f, 0.f, 0.f};

    // zero h dbuf: 512 threads x 16B x 2
    *(f32x4*)(smem + tid * 16) = zero4;
    *(f32x4*)(smem + 8192 + tid * 16) = zero4;

    // stage this wave's 16 n-gate frags into LDS (one-time)
    {
        const b8* nsrc = wsN + (w * 16) * 64 + lane;
        b8* ndst = nlds + (w * 16) * 64 + lane;
        #pragma unroll
        for (int i = 0; i < 16; ++i) ndst[i * 64] = nsrc[i * 64];
    }

    // register-resident A-frags: r,z Whh (32 frags) + Wih (6 frags), PINNED
    b8 whr[2][8], whz[2][8], wir[2], wiz[2], win[2];
    #pragma unroll
    for (int nt = 0; nt < 2; ++nt) {
        #pragma unroll
        for (int kt = 0; kt < 8; ++kt) {
            whr[nt][kt] = wsRZ[((w * 4 + 0 + nt) * 8 + kt) * 64 + lane];
            whz[nt][kt] = wsRZ[((w * 4 + 2 + nt) * 8 + kt) * 64 + lane];
        }
        wir[nt] = wsWI[((w * 3 + 0) * 2 + nt) * 64 + lane];
        wiz[nt] = wsWI[((w * 3 + 1) * 2 + nt) * 64 + lane];
        win[nt] = wsWI[((w * 3 + 2) * 2 + nt) * 64 + lane];
    }
    #pragma unroll
    for (int nt = 0; nt < 2; ++nt) {
        #pragma unroll
        for (int kt = 0; kt < 8; ++kt) {
            asm volatile("" : "+v"(whr[nt][kt]));
            asm volatile("" : "+v"(whz[nt][kt]));
        }
        asm volatile("" : "+v"(wir[nt]));
        asm volatile("" : "+v"(wiz[nt]));
        asm volatile("" : "+v"(win[nt]));
    }

    // bhh_n accumulator-init values, pre-scaled by 2*log2e (C reg j <-> gatech 32w+16nt+4lq+j)
    float4 t0v = *(const float4*)&bhh_f[2 * HDIM + 32 * w + 0  + 4 * lq];
    float4 t1v = *(const float4*)&bhh_f[2 * HDIM + 32 * w + 16 + 4 * lq];
    f32x4 bnv0, bnv1;
    bnv0[0] = L2E2 * t0v.x; bnv0[1] = L2E2 * t0v.y; bnv0[2] = L2E2 * t0v.z; bnv0[3] = L2E2 * t0v.w;
    bnv1[0] = L2E2 * t1v.x; bnv1[1] = L2E2 * t1v.y; bnv1[2] = L2E2 * t1v.z; bnv1[3] = L2E2 * t1v.w;

    // constant part of x B-frag: k=8 -> 1.0 (bias multiplier), rest 0
    b8 xc;
    #pragma unroll
    for (int e = 0; e < 8; ++e) xc[e] = (__bf16)0.0f;
    if (lq == 1) xc[0] = (__bf16)1.0f;

    // h master state in registers: (row=l15, ch=32w+16nt+4lq+j)
    f32x4 h0 = zero4, h1 = zero4;

    const int kswz = (8 * lq) ^ ((l15 & 7) << 3);     // B-read swizzle base
    const int wswz = (l15 & 7) << 3;                  // write swizzle
    const b8* nW = nlds + (w * 16) * 64 + lane;       // this wave's n frags in LDS
    const b8* xRow = xB + (blockRow + l15) * WDIM;

    // prefetch x for t=0
    b8 xf = xc;
    if (lane < 16) xf = xRow[0];

    __syncthreads();

    int cur = 0;
    for (int t = 0; t < WDIM; ++t) {
        // prefetch next step's x early (hides L2 latency under MFMA)
        b8 xn = xc;
        if (lane < 16) xn = xRow[(t + 1) & 127];

        // x-part MFMAs FIRST: register-only operands, fill the post-barrier
        // ds_read latency window; accumulators come out pre-seeded (+ biases via k=8)
        f32x4 aR0 = MFMA(wir[0], xf, zero4);
        f32x4 aR1 = MFMA(wir[1], xf, zero4);
        f32x4 aZ0 = MFMA(wiz[0], xf, zero4);
        f32x4 aZ1 = MFMA(wiz[1], xf, zero4);
        f32x4 aNX0 = MFMA(win[0], xf, zero4);
        f32x4 aNX1 = MFMA(win[1], xf, zero4);
        f32x4 aNH0 = bnv0, aNH1 = bnv1;

        const __bf16* hc = hbB + cur * 4096 + l15 * 256;
        #pragma unroll
        for (int kt = 0; kt < 8; ++kt) {
            b8 hfrag = *(const b8*)(hc + ((kt << 5) ^ kswz));
            b8 n0 = nW[kt * 64];
            b8 n1 = nW[(8 + kt) * 64];
            aR0  = MFMA(whr[0][kt], hfrag, aR0);
            aR1  = MFMA(whr[1][kt], hfrag, aR1);
            aZ0  = MFMA(whz[0][kt], hfrag, aZ0);
            aZ1  = MFMA(whz[1][kt], hfrag, aZ1);
            aNH0 = MFMA(n0, hfrag, aNH0);
            aNH1 = MFMA(n1, hfrag, aNH1);
        }

        // gate fusion: weights pre-scaled (-log2e for r,z; 2*log2e for n) -> raw v_exp_f32
        __bf16* hn = hbB + (cur ^ 1) * 4096;
        b4 v0, v1;
        #pragma unroll
        for (int j = 0; j < 4; ++j) {
            float r = __builtin_amdgcn_rcpf(1.0f + __builtin_amdgcn_exp2f(aR0[j]));
            float z = __builtin_amdgcn_rcpf(1.0f + __builtin_amdgcn_exp2f(aZ0[j]));
            float u = fmaf(r, aNH0[j], aNX0[j]);
            float n = fmaf(-2.0f, __builtin_amdgcn_rcpf(1.0f + __builtin_amdgcn_exp2f(u)), 1.0f);
            float hv = n + z * (h0[j] - n);
            h0[j] = hv; v0[j] = (__bf16)hv;

            r = __builtin_amdgcn_rcpf(1.0f + __builtin_amdgcn_exp2f(aR1[j]));
            z = __builtin_amdgcn_rcpf(1.0f + __builtin_amdgcn_exp2f(aZ1[j]));
            u = fmaf(r, aNH1[j], aNX1[j]);
            n = fmaf(-2.0f, __builtin_amdgcn_rcpf(1.0f + __builtin_amdgcn_exp2f(u)), 1.0f);
            hv = n + z * (h1[j] - n);
            h1[j] = hv; v1[j] = (__bf16)hv;
        }
        *(b4*)(hn + l15 * 256 + ((32 * w + 0  + 4 * lq) ^ wswz)) = v0;
        *(b4*)(hn + l15 * 256 + ((32 * w + 16 + 4 * lq) ^ wswz)) = v1;

        xf = xn;
        cur ^= 1;
        __syncthreads();
    }

    // ---- write forward h (f32 regs) into lastb cols [0,256) ----
    {
        b4 v0, v1;
        #pragma unroll
        for (int j = 0; j < 4; ++j) { v0[j] = (__bf16)h0[j]; v1[j] = (__bf16)h1[j]; }
        *(b4*)(&lastb[l15][0] + ((32 * w + 0  + 4 * lq) ^ wswz)) = v0;
        *(b4*)(&lastb[l15][0] + ((32 * w + 16 + 4 * lq) ^ wswz)) = v1;
    }

    // ---- backward cell (h0=0, one step on x[:,127,:]) -> lastb cols [256,512) ----
    {
        const int trow = tid >> 5;           // 0..15
        const int cb = tid & 31;
        const float4* xr = (const float4*)(x + (blockRow + trow) * WDIM * FDIM + 127 * FDIM);
        float4 xv0 = xr[0], xv1 = xr[1];
        const float4* wb = (const float4*)Wih_b;
        #pragma unroll
        for (int jj = 0; jj < 8; ++jj) {
            int ch = cb + 32 * jj;
            float4 a0 = wb[ch * 2],               a1 = wb[ch * 2 + 1];
            float4 b0 = wb[(HDIM + ch) * 2],      b1 = wb[(HDIM + ch) * 2 + 1];
            float4 c0v = wb[(2 * HDIM + ch) * 2], c1 = wb[(2 * HDIM + ch) * 2 + 1];
            float ir = bih_b[ch]
                + xv0.x * a0.x + xv0.y * a0.y + xv0.z * a0.z + xv0.w * a0.w
                + xv1.x * a1.x + xv1.y * a1.y + xv1.z * a1.z + xv1.w * a1.w;
            float iz = bih_b[HDIM + ch]
                + xv0.x * b0.x + xv0.y * b0.y + xv0.z * b0.z + xv0.w * b0.w
                + xv1.x * b1.x + xv1.y * b1.y + xv1.z * b1.z + xv1.w * b1.w;
            float inn = bih_b[2 * HDIM + ch]
                + xv0.x * c0v.x + xv0.y * c0v.y + xv0.z * c0v.z + xv0.w * c0v.w
                + xv1.x * c1.x + xv1.y * c1.y + xv1.z * c1.z + xv1.w * c1.w;
            float r = sig_(ir + bhh_b[ch]);
            float z = sig_(iz + bhh_b[HDIM + ch]);
            float n = tanh_(fmaf(r, bhh_b[2 * HDIM + ch], inn));
            float hbw = (1.0f - z) * n;
            int c2 = HDIM + ch;
            lastb[trow][c2 ^ ((trow & 7) << 3)] = (__bf16)hbw;
        }
    }
    __syncthreads();

    // ---- projection: y = gelu(last @ Wp^T + bp); wave w -> cols [32w,32w+32) ----
    {
        f32x4 pacc[2];
        #pragma unroll
        for (int nt = 0; nt < 2; ++nt) {
            int col = 32 * w + nt * 16 + l15;
            float b = bp[col];
            pacc[nt][0] = b; pacc[nt][1] = b; pacc[nt][2] = b; pacc[nt][3] = b;
        }
        #pragma unroll
        for (int kt = 0; kt < 16; ++kt) {
            int c = (kt * 32 + lq * 8) ^ ((l15 & 7) << 3);
            b8 a = *(const b8*)&lastb[l15][c];
            #pragma unroll
            for (int nt = 0; nt < 2; ++nt)
                pacc[nt] = MFMA(a, wsWP[((2 * w + nt) * 16 + kt) * 64 + lane], pacc[nt]);
        }
        #pragma unroll
        for (int nt = 0; nt < 2; ++nt) {
            int col = 32 * w + nt * 16 + l15;
            #pragma unroll
            for (int j = 0; j < 4; ++j) {
                int row = lq * 4 + j;
                float v = pacc[nt][j];
                ybuf[row][col] = 0.5f * v * (1.0f + erff(v * 0.70710678118f));
            }
        }
    }
    __syncthreads();

    // ---- LayerNorm: one wave per 2 rows ----
    #pragma unroll
    for (int rr = 0; rr < 2; ++rr) {
        int row = 2 * w + rr;
        float v[4];
        float s = 0.0f, sq = 0.0f;
        #pragma unroll
        for (int m = 0; m < 4; ++m) {
            v[m] = ybuf[row][lane + 64 * m];
            s += v[m];
            sq += v[m] * v[m];
        }
        #pragma unroll
        for (int off = 32; off >= 1; off >>= 1) {
            s  += __shfl_xor(s, off, 64);
            sq += __shfl_xor(sq, off, 64);
        }
        float mu = s * (1.0f / 256.0f);
        float var = sq * (1.0f / 256.0f) - mu * mu;
        float rs = rsqrtf(var + 1e-5f);
        float* orow = out + (blockRow + row) * HDIM;
        #pragma unroll
        for (int m = 0; m < 4; ++m) {
            int cc = lane + 64 * m;
            orow[cc] = (v[m] - mu) * rs * gamma[cc] + beta[cc];
        }
    }
}

extern "C" void kernel_launch(void* const* d_in, const int* in_sizes, int n_in,
                              void* d_out, int out_size, void* d_ws, size_t ws_size,
                              hipStream_t stream)
{
    const float* x     = (const float*)d_in[0];
    const float* Wih_f = (const float*)d_in[1];
    const float* Whh_f = (const float*)d_in[2];
    const float* bih_f = (const float*)d_in[3];
    const float* bhh_f = (const float*)d_in[4];
    const float* Wih_b = (const float*)d_in[5];
    // d_in[6] = Whh_b unused: h0=0 so gh_b = bhh_b exactly
    const float* bih_b = (const float*)d_in[7];
    const float* bhh_b = (const float*)d_in[8];
    const float* Wp    = (const float*)d_in[9];
    const float* bp    = (const float*)d_in[10];
    const float* gamma = (const float*)d_in[11];
    const float* beta  = (const float*)d_in[12];
    float* out = (float*)d_out;
    unsigned char* ws = (unsigned char*)d_ws;

    // allow 144KB dynamic LDS (host-side attribute, graph-capture safe)
    hipFuncSetAttribute((const void*)gru_main_kernel,
                        hipFuncAttributeMaxDynamicSharedMemorySize, SMEM_BYTES);

    const int packItems = 16384 + 8192 + 3072 + 16384 + 262144;   // 306176
    hipLaunchKernelGGL(pack_kernel, dim3((packItems + 255) / 256), dim3(256), 0, stream,
                       x, Wih_f, Whh_f, bih_f, bhh_f, Wp, ws);
    hipLaunchKernelGGL(gru_main_kernel, dim3(BDIM / 16), dim3(512), SMEM_BYTES, stream,
                       x, bhh_f, Wih_b, bih_b, bhh_b, bp, gamma, beta, ws, out);
}